// Round 13
// baseline (168.858 us; speedup 1.0000x reference)
//
#include <hip/hip_runtime.h>
#include <hip/hip_bf16.h>

#define HID 128
#define NB2MAX 128  // 1024-node buckets, N up to 131072

typedef __bf16 bf16x8 __attribute__((ext_vector_type(8)));
typedef float f32x4 __attribute__((ext_vector_type(4)));
typedef float f32x2 __attribute__((ext_vector_type(2)));

#if defined(__has_builtin)
#if __has_builtin(__builtin_amdgcn_cvt_pk_f32_fp8) && __has_builtin(__builtin_amdgcn_cvt_pk_fp8_f32)
#define HAVE_FP8_CVT 1
#endif
#endif
#ifndef HAVE_FP8_CVT
#define HAVE_FP8_CVT 0
#include <hip/hip_fp8.h>
#endif

__device__ __forceinline__ float b2f(unsigned int u) { return __uint_as_float(u << 16); }
__device__ __forceinline__ unsigned int f2b(float f) {
  unsigned int b = __float_as_uint(f);
  return (b + 0x7FFFu + ((b >> 16) & 1u)) >> 16;
}
__device__ __forceinline__ unsigned int pack2(float lo, float hi) {
  return f2b(lo) | (f2b(hi) << 16);
}

#if !HAVE_FP8_CVT
__device__ __forceinline__ float fp8dec(unsigned int u) {
  unsigned int e = (u >> 3) & 15, m = u & 7, sgn = (u >> 7) & 1;
  float v;
  if (e) v = __uint_as_float(((e + 120) << 23) | (m << 20));
  else v = (float)m * 0.001953125f;
  return sgn ? -v : v;
}
#endif

__device__ __forceinline__ unsigned int pk4_fp8(float v0, float v1, float v2, float v3) {
#if HAVE_FP8_CVT
  int pk = 0;
  pk = __builtin_amdgcn_cvt_pk_fp8_f32(v0, v1, pk, false);
  pk = __builtin_amdgcn_cvt_pk_fp8_f32(v2, v3, pk, true);
  return (unsigned int)pk;
#else
  __hip_fp8_e4m3 a(v0), b(v1), c(v2), d(v3);
  return (unsigned)a.__x | ((unsigned)b.__x << 8) | ((unsigned)c.__x << 16) |
         ((unsigned)d.__x << 24);
#endif
}

__device__ __forceinline__ void acc4_fp8(unsigned int u, float* a) {
#if HAVE_FP8_CVT
  f32x2 lo = __builtin_amdgcn_cvt_pk_f32_fp8((int)u, false);
  f32x2 hi = __builtin_amdgcn_cvt_pk_f32_fp8((int)u, true);
  a[0] += lo.x; a[1] += lo.y; a[2] += hi.x; a[3] += hi.y;
#else
  a[0] += fp8dec(u & 255); a[1] += fp8dec((u >> 8) & 255);
  a[2] += fp8dec((u >> 16) & 255); a[3] += fp8dec((u >> 24) & 255);
#endif
}

// ---------------- one-pass bucketed scatter, LINE-ALIGNED per-(block,bucket) runs ----------
// pairsp runs rounded to 16 entries (64 B), srcb runs rounded to 32 (64 B); pad = sentinel.
__global__ void k_scatter2(const int* __restrict__ src, const int* __restrict__ dst, int E,
                           int NB2, int CAP, int* __restrict__ curd, int* __restrict__ curs,
                           int* __restrict__ pairsp, unsigned short* __restrict__ srcb) {
  __shared__ int hd[NB2MAX], hs[NB2MAX], bd[NB2MAX], bs[NB2MAX];
  for (int i = threadIdx.x; i < NB2; i += 256) { hd[i] = 0; hs[i] = 0; }
  __syncthreads();
  int per = (E + gridDim.x - 1) / gridDim.x;
  int begin = blockIdx.x * per;
  int end = min(E, begin + per);
  for (int e = begin + threadIdx.x; e < end; e += 256) {
    atomicAdd(&hd[dst[e] >> 10], 1);
    atomicAdd(&hs[src[e] >> 10], 1);
  }
  __syncthreads();
  for (int i = threadIdx.x; i < NB2; i += 256) {
    int cd = hd[i], cs_ = hs[i];
    bd[i] = cd ? atomicAdd(&curd[i], (cd + 15) & ~15) : 0;
    bs[i] = cs_ ? atomicAdd(&curs[i], (cs_ + 31) & ~31) : 0;
    hd[i] = 0; hs[i] = 0;
  }
  __syncthreads();
  for (int e = begin + threadIdx.x; e < end; e += 256) {
    int d = dst[e], s = src[e];
    int bD = d >> 10, bS = s >> 10;
    int offD = bd[bD] + atomicAdd(&hd[bD], 1);
    if (offD < CAP) pairsp[(size_t)bD * CAP + offD] = (s << 10) | (d & 1023);
    int offS = bs[bS] + atomicAdd(&hs[bS], 1);
    if (offS < CAP) srcb[(size_t)bS * CAP + offS] = (unsigned short)(s & 1023);
  }
  __syncthreads();
  // sentinel-fill the padding so runs end on line boundaries
  for (int i = threadIdx.x; i < NB2; i += 256) {
    int cd = hd[i], rd = (cd + 15) & ~15;
    for (int j = cd; j < rd; j++) {
      int pos = bd[i] + j;
      if (pos < CAP) pairsp[(size_t)i * CAP + pos] = -1;
    }
    int cs_ = hs[i], rs = (cs_ + 31) & ~31;
    for (int j = cs_; j < rs; j++) {
      int pos = bs[i] + j;
      if (pos < CAP) srcb[(size_t)i * CAP + pos] = 0xFFFFu;
    }
  }
}

// ---------------- split phases: [0,NB2)=out-degree; [NB2,2NB2)=CSR; [2NB2,..)=prepW ----
__global__ __launch_bounds__(1024) void k_degcsr(
    const unsigned short* __restrict__ srcb, const int* __restrict__ curs,
    const int* __restrict__ pairsp, const int* __restrict__ curd, int NB2, int CAP, int N,
    int* __restrict__ degsrc, int* __restrict__ bmax, int2* __restrict__ rowptr2,
    float* __restrict__ dinv, int* __restrict__ colarr,
    const float* __restrict__ W2, unsigned short* __restrict__ W2T) {
  __shared__ int cnt[1024], cur[1024];
  __shared__ int wsum[16];
  int tid = threadIdx.x;
  if ((int)blockIdx.x >= 2 * NB2) {
    int idx = (blockIdx.x - 2 * NB2) * 1024 + tid;
    if (idx < 128 * 128) {
      int j = idx >> 7, k = idx & 127;
      W2T[j * 128 + k] = (unsigned short)f2b(W2[k * 128 + j]);
    }
    return;
  }
  if ((int)blockIdx.x < NB2) {
    // phase A: out-degree histogram for src-bucket b (skip sentinels)
    int b = blockIdx.x;
    int g = (b << 10) + tid;
    int lo = b * CAP;
    cnt[tid] = 0; __syncthreads();
    int szS = min(curs[b], CAP);
    const unsigned short* sb = srcb + (size_t)lo;
    for (int k = tid; k < szS; k += 1024) {
      unsigned int v = sb[k];
      if (v < 1024u) atomicAdd(&cnt[v], 1);
    }
    __syncthreads();
    int c = cnt[tid];
    if (g < N) degsrc[g] = c;
    // wave max-reduce
    int m = (g < N) ? c : 0;
    for (int d = 32; d > 0; d >>= 1) m = max(m, __shfl_xor(m, d));
    if ((tid & 63) == 0) wsum[tid >> 6] = m;
    __syncthreads();
    if (tid == 0) {
      int mm = 0;
#pragma unroll
      for (int i = 0; i < 16; i++) mm = max(mm, wsum[i]);
      bmax[b] = mm;
    }
    return;
  }
  // phase B: CSR build for dst-bucket b (skip sentinels)
  int b = blockIdx.x - NB2;
  int g = (b << 10) + tid;
  int lo = b * CAP;
  cnt[tid] = 0; __syncthreads();
  int szD = min(curd[b], CAP);
  const int* pb = pairsp + (size_t)lo;
  for (int k = tid; k < szD; k += 1024) {
    int p = pb[k];
    if (p != -1) atomicAdd(&cnt[p & 1023], 1);
  }
  __syncthreads();
  int c = cnt[tid];
  // wave shfl inclusive scan + cross-wave
  int lane = tid & 63, wid = tid >> 6;
  int sv = c;
  for (int d = 1; d < 64; d <<= 1) {
    int t = __shfl_up(sv, d);
    if (lane >= d) sv += t;
  }
  if (lane == 63) wsum[wid] = sv;
  __syncthreads();
  if (tid < 16) {
    int w = wsum[tid];
    for (int d = 1; d < 16; d <<= 1) {
      int t = __shfl_up(w, d, 16);
      if (tid >= d) w += t;
    }
    wsum[tid] = w;
  }
  __syncthreads();
  int incl = sv + (wid ? wsum[wid - 1] : 0);
  int excl = incl - c;
  if (g < N) {
    rowptr2[g] = make_int2(lo + excl, lo + excl + c);
    dinv[g] = rsqrtf((float)(c + 1));
  }
  cur[tid] = lo + excl;
  __syncthreads();
  for (int k = tid; k < szD; k += 1024) {
    int p = pb[k];
    if (p == -1) continue;
    int pos = atomicAdd(&cur[p & 1023], 1);
    colarr[pos] = ((unsigned)p) >> 10;
  }
}

// node features prescaled by own dinv (inline global bmax reduction over NB2<=128)
__global__ void k_node(const float* __restrict__ coords, const int* __restrict__ degsrc,
                       const float* __restrict__ dinv, const int* __restrict__ bmax, int NB2,
                       int N, float4* __restrict__ x0s) {
  __shared__ int sm[128];
  int tid = threadIdx.x;
  if (tid < 128) sm[tid] = (tid < NB2) ? bmax[tid] : 0;
  __syncthreads();
  if (tid < 64) { sm[tid] = max(sm[tid], sm[tid + 64]); }
  __syncthreads();
  if (tid < 32) { sm[tid] = max(sm[tid], sm[tid + 32]); }
  __syncthreads();
  if (tid < 16) { sm[tid] = max(sm[tid], sm[tid + 16]); }
  __syncthreads();
  if (tid < 8) { sm[tid] = max(sm[tid], sm[tid + 8]); }
  __syncthreads();
  if (tid < 4) { sm[tid] = max(sm[tid], sm[tid + 4]); }
  __syncthreads();
  if (tid < 2) { sm[tid] = max(sm[tid], sm[tid + 2]); }
  __syncthreads();
  if (tid == 0) sm[0] = max(sm[0], sm[1]);
  __syncthreads();
  float inv = 1.0f / (float)max(sm[0], 1);
  int n = blockIdx.x * 256 + tid;
  if (n >= N) return;
  float di = dinv[n];
  float4 v;
  v.x = coords[n * 2 + 0] * di;
  v.y = coords[n * 2 + 1] * di;
  v.z = (float)degsrc[n] * inv * di;
  v.w = 0.f;
  x0s[n] = v;
}

// ---------------- fused layer-1: aggregate 3 feats + linear + relu + prescale -> fp8 ----
__global__ void k_agg3lin(const float4* __restrict__ x0s, const float* __restrict__ dinv,
                          const int2* __restrict__ rowptr2, const int* __restrict__ col,
                          const float* __restrict__ W1, const float* __restrict__ b1, int N,
                          unsigned int* __restrict__ x1f8) {
  __shared__ float w0s[128], w1s[128], w2s[128], bsm[128];
  for (int t = threadIdx.x; t < 128; t += 256) {
    w0s[t] = W1[t];
    w1s[t] = W1[128 + t];
    w2s[t] = W1[256 + t];
    bsm[t] = b1[t];
  }
  __syncthreads();
  int n = blockIdx.x * 256 + threadIdx.x;
  if (n >= N) return;
  float4 a = x0s[n];
  int2 rp = rowptr2[n];
  int k = rp.x, en = rp.y;
  for (; k + 3 < en; k += 4) {
    int s0 = col[k], s1 = col[k + 1], s2 = col[k + 2], s3 = col[k + 3];
    float4 w0 = x0s[s0];
    float4 w1 = x0s[s1];
    float4 w2 = x0s[s2];
    float4 w3 = x0s[s3];
    a.x += (w0.x + w1.x) + (w2.x + w3.x);
    a.y += (w0.y + w1.y) + (w2.y + w3.y);
    a.z += (w0.z + w1.z) + (w2.z + w3.z);
  }
  for (; k < en; k++) {
    float4 w = x0s[col[k]];
    a.x += w.x; a.y += w.y; a.z += w.z;
  }
  float di = dinv[n];
  float ax = a.x * di, ay = a.y * di, az = a.z * di;
  unsigned int* orow = x1f8 + (size_t)n * 32;
#pragma unroll 8
  for (int f0 = 0; f0 < 128; f0 += 4) {
    float v0 = fmaxf(bsm[f0] + ax * w0s[f0] + ay * w1s[f0] + az * w2s[f0], 0.f) * di;
    float v1 = fmaxf(bsm[f0 + 1] + ax * w0s[f0 + 1] + ay * w1s[f0 + 1] + az * w2s[f0 + 1], 0.f) * di;
    float v2 = fmaxf(bsm[f0 + 2] + ax * w0s[f0 + 2] + ay * w1s[f0 + 2] + az * w2s[f0 + 2], 0.f) * di;
    float v3 = fmaxf(bsm[f0 + 3] + ax * w0s[f0 + 3] + ay * w1s[f0 + 3] + az * w2s[f0 + 3], 0.f) * di;
    orow[f0 >> 2] = pk4_fp8(v0, v1, v2, v3);
  }
}

// ---------------- GCN layer 2 aggregation: fp8 gather, 8 lanes/node x uint4, 4-deep ----
__global__ void k_agg128(const unsigned int* __restrict__ x1f8, const float* __restrict__ dinv,
                         const int2* __restrict__ rowptr2, const int* __restrict__ col,
                         int N, unsigned short* __restrict__ xa) {
  int g = (int)((blockIdx.x * 256 + threadIdx.x) >> 3);
  int lane = threadIdx.x & 7;
  if (g >= N) return;
  const uint4* base = (const uint4*)x1f8 + lane;  // row stride = 8 uint4 (128 B)
  float acc[16];
#pragma unroll
  for (int i = 0; i < 16; i++) acc[i] = 0.f;
  uint4 self = base[(size_t)g * 8];
  acc4_fp8(self.x, acc); acc4_fp8(self.y, acc + 4);
  acc4_fp8(self.z, acc + 8); acc4_fp8(self.w, acc + 12);
  int2 rp = rowptr2[g];
  int k = rp.x, en = rp.y;
  for (; k + 3 < en; k += 4) {
    int s0 = col[k], s1 = col[k + 1], s2 = col[k + 2], s3 = col[k + 3];
    uint4 w0 = base[(size_t)s0 * 8];
    uint4 w1 = base[(size_t)s1 * 8];
    uint4 w2 = base[(size_t)s2 * 8];
    uint4 w3 = base[(size_t)s3 * 8];
    acc4_fp8(w0.x, acc); acc4_fp8(w0.y, acc + 4); acc4_fp8(w0.z, acc + 8); acc4_fp8(w0.w, acc + 12);
    acc4_fp8(w1.x, acc); acc4_fp8(w1.y, acc + 4); acc4_fp8(w1.z, acc + 8); acc4_fp8(w1.w, acc + 12);
    acc4_fp8(w2.x, acc); acc4_fp8(w2.y, acc + 4); acc4_fp8(w2.z, acc + 8); acc4_fp8(w2.w, acc + 12);
    acc4_fp8(w3.x, acc); acc4_fp8(w3.y, acc + 4); acc4_fp8(w3.z, acc + 8); acc4_fp8(w3.w, acc + 12);
  }
  for (; k < en; k++) {
    uint4 w = base[(size_t)col[k] * 8];
    acc4_fp8(w.x, acc); acc4_fp8(w.y, acc + 4); acc4_fp8(w.z, acc + 8); acc4_fp8(w.w, acc + 12);
  }
  float di = dinv[g];
  uint4 o1, o2;
  o1.x = pack2(acc[0] * di, acc[1] * di);
  o1.y = pack2(acc[2] * di, acc[3] * di);
  o1.z = pack2(acc[4] * di, acc[5] * di);
  o1.w = pack2(acc[6] * di, acc[7] * di);
  o2.x = pack2(acc[8] * di, acc[9] * di);
  o2.y = pack2(acc[10] * di, acc[11] * di);
  o2.z = pack2(acc[12] * di, acc[13] * di);
  o2.w = pack2(acc[14] * di, acc[15] * di);
  uint4* op = (uint4*)xa + (size_t)g * 16 + lane * 2;
  op[0] = o1;
  op[1] = o2;
}

// ---------------- layer 2 GEMM via MFMA, fused heads + colsum (x2 never stored) ----------
__global__ __launch_bounds__(256) void k_gemm2(const unsigned short* __restrict__ xab,
                                               const unsigned short* __restrict__ W2T,
                                               const float* __restrict__ b2,
                                               const float* __restrict__ Ws,
                                               const float* __restrict__ bs,
                                               const float* __restrict__ Wmu,
                                               const float* __restrict__ bmu,
                                               const float* __restrict__ Wls,
                                               const float* __restrict__ bls,
                                               int N, float* __restrict__ s_arr,
                                               float* __restrict__ out,
                                               float* __restrict__ partials) {
  __shared__ float w[640];
  __shared__ float cs[4][128];
  for (int t = threadIdx.x; t < 128; t += 256) {
    w[t] = Ws[t];
    w[128 + t] = Wmu[t * 2 + 0];
    w[256 + t] = Wmu[t * 2 + 1];
    w[384 + t] = Wls[t * 2 + 0];
    w[512 + t] = Wls[t * 2 + 1];
  }
  __syncthreads();
  int wv = threadIdx.x >> 6;
  int lane = threadIdx.x & 63;
  int l15 = lane & 15, lhi = lane >> 4;
  int rowbase = blockIdx.x * 64 + wv * 16;
  int arow = rowbase + l15;
  int arowc = min(arow, N - 1);
  const unsigned short* ap = xab + (size_t)arowc * HID + lhi * 8;
  bf16x8 a[4];
#pragma unroll
  for (int kk = 0; kk < 4; kk++) a[kk] = *(const bf16x8*)(ap + kk * 32);
  float cpart[8];
  float p0[4] = {0, 0, 0, 0}, p1[4] = {0, 0, 0, 0}, p2[4] = {0, 0, 0, 0};
  float p3[4] = {0, 0, 0, 0}, p4[4] = {0, 0, 0, 0};
#pragma unroll
  for (int ct = 0; ct < 8; ct++) {
    f32x4 acc = {0.f, 0.f, 0.f, 0.f};
    const unsigned short* bp = W2T + (size_t)(ct * 16 + l15) * HID + lhi * 8;
#pragma unroll
    for (int kk = 0; kk < 4; kk++) {
      bf16x8 bfr = *(const bf16x8*)(bp + kk * 32);
      acc = __builtin_amdgcn_mfma_f32_16x16x32_bf16(a[kk], bfr, acc, 0, 0, 0);
    }
    int cidx = ct * 16 + l15;
    float bias = b2[cidx];
    float ws_ = w[cidx];
    float wm0 = w[128 + cidx], wm1 = w[256 + cidx];
    float wl0 = w[384 + cidx], wl1 = w[512 + cidx];
    float cl = 0.f;
#pragma unroll
    for (int r = 0; r < 4; r++) {
      int node = rowbase + lhi * 4 + r;
      float o = fmaxf(acc[r] + bias, 0.f);
      if (node < N) cl += o;
      p0[r] += o * ws_;
      p1[r] += o * wm0;
      p2[r] += o * wm1;
      p3[r] += o * wl0;
      p4[r] += o * wl1;
    }
    cl += __shfl_xor(cl, 16);
    cl += __shfl_xor(cl, 32);
    cpart[ct] = cl;
  }
#pragma unroll
  for (int r = 0; r < 4; r++) {
#pragma unroll
    for (int m = 1; m < 16; m <<= 1) {
      p0[r] += __shfl_xor(p0[r], m);
      p1[r] += __shfl_xor(p1[r], m);
      p2[r] += __shfl_xor(p2[r], m);
      p3[r] += __shfl_xor(p3[r], m);
      p4[r] += __shfl_xor(p4[r], m);
    }
  }
  if (l15 == 0) {
#pragma unroll
    for (int r = 0; r < 4; r++) {
      int node = rowbase + lhi * 4 + r;
      if (node < N) {
        s_arr[node] = p0[r] + bs[0];
        out[(size_t)N + node * 2 + 0] = p1[r] + bmu[0];
        out[(size_t)N + node * 2 + 1] = p2[r] + bmu[1];
        out[(size_t)3 * N + node * 2 + 0] = fminf(fmaxf(p3[r] + bls[0], -4.f), 2.f);
        out[(size_t)3 * N + node * 2 + 1] = fminf(fmaxf(p4[r] + bls[1], -4.f), 2.f);
      }
    }
  }
  if (lane < 16) {
#pragma unroll
    for (int ct = 0; ct < 8; ct++) cs[wv][ct * 16 + lane] = cpart[ct];
  }
  __syncthreads();
  if (threadIdx.x < 128) {
    int f = threadIdx.x;
    partials[(size_t)blockIdx.x * 128 + f] = cs[0][f] + cs[1][f] + cs[2][f] + cs[3][f];
  }
}

// ---------------- merged: online-LSE partials (blocks 0..255) + colsum reduce (256..319) ----
__global__ void k_lse_colsum(const float* __restrict__ s, int N, float* __restrict__ pm,
                             float* __restrict__ pt, const float* __restrict__ partials,
                             int nblkG, float* __restrict__ colsum) {
  if (blockIdx.x >= 256) {
    int bb = blockIdx.x - 256;
    int f = threadIdx.x;
    if (f < 128) {
      float t = 0.f;
      for (int b = bb; b < nblkG; b += 64) t += partials[(size_t)b * 128 + f];
      atomicAdd(&colsum[f], t);
    }
    return;
  }
  __shared__ float smM[256], smT[256];
  float m = -1e30f, t = 0.f;
  for (int i = blockIdx.x * 256 + threadIdx.x; i < N; i += 256 * 256) {
    float v = s[i];
    if (v > m) { t = t * __expf(m - v) + 1.f; m = v; }
    else t += __expf(v - m);
  }
  smM[threadIdx.x] = m; smT[threadIdx.x] = t; __syncthreads();
  for (int st = 128; st > 0; st >>= 1) {
    if (threadIdx.x < st) {
      float m2 = smM[threadIdx.x + st], t2 = smT[threadIdx.x + st];
      float m1 = smM[threadIdx.x], t1 = smT[threadIdx.x];
      float M = fmaxf(m1, m2);
      smM[threadIdx.x] = M;
      smT[threadIdx.x] = t1 * __expf(m1 - M) + t2 * __expf(m2 - M);
    }
    __syncthreads();
  }
  if (threadIdx.x == 0) { pm[blockIdx.x] = smM[0]; pt[blockIdx.x] = smT[0]; }
}

// ---------------- merged: logits (inline LSE finish) + value head (last block) ----------
__global__ void k_logits_value(const float* __restrict__ sarr, const float* __restrict__ pm,
                               const float* __restrict__ pt, int N, float* __restrict__ out,
                               const float* __restrict__ colsum, const float* __restrict__ Wv1,
                               const float* __restrict__ bv1, const float* __restrict__ Wv2,
                               const float* __restrict__ bv2, int nblkN) {
  if ((int)blockIdx.x == nblkN) {
    __shared__ float hid[64];
    float invN = 1.0f / (float)N;
    int j = threadIdx.x;
    if (j < 64) {
      float a = bv1[j];
      for (int f = 0; f < 128; f++) a += (colsum[f] * invN) * Wv1[f * 64 + j];
      hid[j] = fmaxf(a, 0.f) * Wv2[j];
    }
    __syncthreads();
    if (threadIdx.x == 0) {
      float v = bv2[0];
      for (int jj = 0; jj < 64; jj++) v += hid[jj];
      out[(size_t)5 * N] = v;
    }
    return;
  }
  __shared__ float smM[256], smT[256];
  smM[threadIdx.x] = pm[threadIdx.x];
  smT[threadIdx.x] = pt[threadIdx.x];
  __syncthreads();
  for (int st = 128; st > 0; st >>= 1) {
    if (threadIdx.x < st) {
      float m2 = smM[threadIdx.x + st], t2 = smT[threadIdx.x + st];
      float m1 = smM[threadIdx.x], t1 = smT[threadIdx.x];
      float M = fmaxf(m1, m2);
      smM[threadIdx.x] = M;
      smT[threadIdx.x] = t1 * __expf(m1 - M) + t2 * __expf(m2 - M);
    }
    __syncthreads();
  }
  float lse = smM[0] + logf(smT[0]);
  int n = blockIdx.x * 256 + threadIdx.x;
  if (n < N) out[n] = sarr[n] - lse;
}

extern "C" void kernel_launch(void* const* d_in, const int* in_sizes, int n_in,
                              void* d_out, int out_size, void* d_ws, size_t ws_size,
                              hipStream_t stream) {
  const float* coords = (const float*)d_in[0];
  const int* ei = (const int*)d_in[1];
  const float* W1 = (const float*)d_in[2];
  const float* b1 = (const float*)d_in[3];
  const float* W2 = (const float*)d_in[4];
  const float* b2 = (const float*)d_in[5];
  const float* Wsw = (const float*)d_in[6];
  const float* bsw = (const float*)d_in[7];
  const float* Wmu = (const float*)d_in[8];
  const float* bmu = (const float*)d_in[9];
  const float* Wls = (const float*)d_in[10];
  const float* bls = (const float*)d_in[11];
  const float* Wv1 = (const float*)d_in[12];
  const float* bv1 = (const float*)d_in[13];
  const float* Wv2 = (const float*)d_in[14];
  const float* bv2 = (const float*)d_in[15];
  int N = in_sizes[0] / 2;
  int E = in_sizes[1] / 2;
  const int* src = ei;
  const int* dst = ei + E;
  float* outf = (float*)d_out;
  int NB2 = (N + 1023) >> 10;
  // extra headroom for line-alignment padding: up to 512 blocks * 32 entries
  int CAP = ((E / NB2) * 5 / 4 + 512 * 32 + 1024 + 255) & ~255;
  int nblkG = (N + 63) / 64;
  int nblkN = (N + 255) / 256;

  char* base = (char*)d_ws;
  size_t off = 0;
  auto alloc = [&](size_t bytes) -> void* {
    void* r = base + off;
    off += (bytes + 255) & ~(size_t)255;
    return r;
  };
  size_t zero_start = off;
  int* curd = (int*)alloc((size_t)NB2 * 4);
  int* curs = (int*)alloc((size_t)NB2 * 4);
  float* colsum = (float*)alloc(128 * 4);
  size_t zero_bytes = off - zero_start;
  int* bmax = (int*)alloc((size_t)NB2 * 4);
  int2* rowptr2 = (int2*)alloc((size_t)N * 8);
  int* pairsp = (int*)alloc((size_t)NB2 * CAP * 4);
  unsigned short* srcb = (unsigned short*)alloc((size_t)NB2 * CAP * 2);
  int* colarr = (int*)alloc((size_t)NB2 * CAP * 4);
  int* degsrc = (int*)alloc((size_t)N * 4);
  float* dinv = (float*)alloc((size_t)N * 4);
  float4* x0s = (float4*)alloc((size_t)N * 16);
  float* sarr = (float*)alloc((size_t)N * 4);
  float* pm = (float*)alloc(256 * 4);
  float* pt = (float*)alloc(256 * 4);
  unsigned short* W2T = (unsigned short*)alloc(128 * 128 * 2);
  float* partials = (float*)alloc((size_t)nblkG * 128 * 4);
  unsigned int* x1f8 = (unsigned int*)alloc((size_t)N * 128);      // fp8 e4m3, N x 128
  unsigned short* xab = (unsigned short*)alloc((size_t)N * HID * 2);
  if (off > ws_size) return;

  hipMemsetAsync(base + zero_start, 0, zero_bytes, stream);
  k_scatter2<<<512, 256, 0, stream>>>(src, dst, E, NB2, CAP, curd, curs, pairsp, srcb);
  k_degcsr<<<2 * NB2 + 16, 1024, 0, stream>>>(srcb, curs, pairsp, curd, NB2, CAP, N, degsrc,
                                              bmax, rowptr2, dinv, colarr, W2, W2T);
  k_node<<<nblkN, 256, 0, stream>>>(coords, degsrc, dinv, bmax, NB2, N, x0s);
  k_agg3lin<<<nblkN, 256, 0, stream>>>(x0s, dinv, rowptr2, colarr, W1, b1, N, x1f8);
  k_agg128<<<(N * 8 + 255) / 256, 256, 0, stream>>>(x1f8, dinv, rowptr2, colarr, N, xab);
  k_gemm2<<<nblkG, 256, 0, stream>>>(xab, W2T, b2, Wsw, bsw, Wmu, bmu, Wls, bls, N, sarr, outf,
                                     partials);
  k_lse_colsum<<<320, 256, 0, stream>>>(sarr, N, pm, pt, partials, nblkG, colsum);
  k_logits_value<<<nblkN + 1, 256, 0, stream>>>(sarr, pm, pt, N, outf, colsum, Wv1, bv1, Wv2,
                                                bv2, nblkN);
}

// Round 14
// 162.647 us; speedup vs baseline: 1.0382x; 1.0382x over previous
//
#include <hip/hip_runtime.h>
#include <hip/hip_bf16.h>

#define HID 128
#define NB2MAX 128  // 1024-node buckets, N up to 131072

typedef __bf16 bf16x8 __attribute__((ext_vector_type(8)));
typedef float f32x4 __attribute__((ext_vector_type(4)));
typedef float f32x2 __attribute__((ext_vector_type(2)));

#if defined(__has_builtin)
#if __has_builtin(__builtin_amdgcn_cvt_pk_f32_fp8) && __has_builtin(__builtin_amdgcn_cvt_pk_fp8_f32)
#define HAVE_FP8_CVT 1
#endif
#endif
#ifndef HAVE_FP8_CVT
#define HAVE_FP8_CVT 0
#include <hip/hip_fp8.h>
#endif

__device__ __forceinline__ float b2f(unsigned int u) { return __uint_as_float(u << 16); }
__device__ __forceinline__ unsigned int f2b(float f) {
  unsigned int b = __float_as_uint(f);
  return (b + 0x7FFFu + ((b >> 16) & 1u)) >> 16;
}
__device__ __forceinline__ unsigned int pack2(float lo, float hi) {
  return f2b(lo) | (f2b(hi) << 16);
}

#if !HAVE_FP8_CVT
__device__ __forceinline__ float fp8dec(unsigned int u) {
  unsigned int e = (u >> 3) & 15, m = u & 7, sgn = (u >> 7) & 1;
  float v;
  if (e) v = __uint_as_float(((e + 120) << 23) | (m << 20));
  else v = (float)m * 0.001953125f;
  return sgn ? -v : v;
}
#endif

__device__ __forceinline__ unsigned int pk4_fp8(float v0, float v1, float v2, float v3) {
#if HAVE_FP8_CVT
  int pk = 0;
  pk = __builtin_amdgcn_cvt_pk_fp8_f32(v0, v1, pk, false);
  pk = __builtin_amdgcn_cvt_pk_fp8_f32(v2, v3, pk, true);
  return (unsigned int)pk;
#else
  __hip_fp8_e4m3 a(v0), b(v1), c(v2), d(v3);
  return (unsigned)a.__x | ((unsigned)b.__x << 8) | ((unsigned)c.__x << 16) |
         ((unsigned)d.__x << 24);
#endif
}

__device__ __forceinline__ void acc4_fp8(unsigned int u, float* a) {
#if HAVE_FP8_CVT
  f32x2 lo = __builtin_amdgcn_cvt_pk_f32_fp8((int)u, false);
  f32x2 hi = __builtin_amdgcn_cvt_pk_f32_fp8((int)u, true);
  a[0] += lo.x; a[1] += lo.y; a[2] += hi.x; a[3] += hi.y;
#else
  a[0] += fp8dec(u & 255); a[1] += fp8dec((u >> 8) & 255);
  a[2] += fp8dec((u >> 16) & 255); a[3] += fp8dec((u >> 24) & 255);
#endif
}

// ---------------- one-pass bucketed scatter into fixed-CAP regions ----------------
__global__ void k_scatter2(const int* __restrict__ src, const int* __restrict__ dst, int E,
                           int NB2, int CAP, int* __restrict__ curd, int* __restrict__ curs,
                           int* __restrict__ pairsp, unsigned short* __restrict__ srcb) {
  __shared__ int hd[NB2MAX], hs[NB2MAX], bd[NB2MAX], bs[NB2MAX];
  for (int i = threadIdx.x; i < NB2; i += 256) { hd[i] = 0; hs[i] = 0; }
  __syncthreads();
  int per = (E + gridDim.x - 1) / gridDim.x;
  int begin = blockIdx.x * per;
  int end = min(E, begin + per);
  for (int e = begin + threadIdx.x; e < end; e += 256) {
    atomicAdd(&hd[dst[e] >> 10], 1);
    atomicAdd(&hs[src[e] >> 10], 1);
  }
  __syncthreads();
  for (int i = threadIdx.x; i < NB2; i += 256) {
    bd[i] = hd[i] ? atomicAdd(&curd[i], hd[i]) : 0;
    bs[i] = hs[i] ? atomicAdd(&curs[i], hs[i]) : 0;
    hd[i] = 0; hs[i] = 0;
  }
  __syncthreads();
  for (int e = begin + threadIdx.x; e < end; e += 256) {
    int d = dst[e], s = src[e];
    int bD = d >> 10, bS = s >> 10;
    int offD = bd[bD] + atomicAdd(&hd[bD], 1);
    if (offD < CAP) pairsp[(size_t)bD * CAP + offD] = (s << 10) | (d & 1023);
    int offS = bs[bS] + atomicAdd(&hs[bS], 1);
    if (offS < CAP) srcb[(size_t)bS * CAP + offS] = (unsigned short)(s & 1023);
  }
}

// ---------------- split phases: [0,NB2)=out-degree; [NB2,2NB2)=CSR; [2NB2,..)=prepW ----
__global__ __launch_bounds__(1024) void k_degcsr(
    const unsigned short* __restrict__ srcb, const int* __restrict__ curs,
    const int* __restrict__ pairsp, const int* __restrict__ curd, int NB2, int CAP, int N,
    int* __restrict__ degsrc, int* __restrict__ bmax, int2* __restrict__ rowptr2,
    float* __restrict__ dinv, int* __restrict__ colarr,
    const float* __restrict__ W2, unsigned short* __restrict__ W2T) {
  __shared__ int cnt[1024], cur[1024];
  __shared__ int wsum[16];
  int tid = threadIdx.x;
  if ((int)blockIdx.x >= 2 * NB2) {
    int idx = (blockIdx.x - 2 * NB2) * 1024 + tid;
    if (idx < 128 * 128) {
      int j = idx >> 7, k = idx & 127;
      W2T[j * 128 + k] = (unsigned short)f2b(W2[k * 128 + j]);
    }
    return;
  }
  if ((int)blockIdx.x < NB2) {
    // phase A: out-degree histogram for src-bucket b
    int b = blockIdx.x;
    int g = (b << 10) + tid;
    int lo = b * CAP;
    cnt[tid] = 0; __syncthreads();
    int szS = min(curs[b], CAP);
    const unsigned short* sb = srcb + (size_t)lo;
    for (int k = tid; k < szS; k += 1024) atomicAdd(&cnt[sb[k]], 1);
    __syncthreads();
    int c = cnt[tid];
    if (g < N) degsrc[g] = c;
    int m = (g < N) ? c : 0;
    for (int d = 32; d > 0; d >>= 1) m = max(m, __shfl_xor(m, d));
    if ((tid & 63) == 0) wsum[tid >> 6] = m;
    __syncthreads();
    if (tid == 0) {
      int mm = 0;
#pragma unroll
      for (int i = 0; i < 16; i++) mm = max(mm, wsum[i]);
      bmax[b] = mm;
    }
    return;
  }
  // phase B: CSR build for dst-bucket b
  int b = blockIdx.x - NB2;
  int g = (b << 10) + tid;
  int lo = b * CAP;
  cnt[tid] = 0; __syncthreads();
  int szD = min(curd[b], CAP);
  const int* pb = pairsp + (size_t)lo;
  for (int k = tid; k < szD; k += 1024) atomicAdd(&cnt[pb[k] & 1023], 1);
  __syncthreads();
  int c = cnt[tid];
  // wave shfl inclusive scan + cross-wave combine
  int lane = tid & 63, wid = tid >> 6;
  int sv = c;
  for (int d = 1; d < 64; d <<= 1) {
    int t = __shfl_up(sv, d);
    if (lane >= d) sv += t;
  }
  if (lane == 63) wsum[wid] = sv;
  __syncthreads();
  if (tid < 16) {
    int w = wsum[tid];
    for (int d = 1; d < 16; d <<= 1) {
      int t = __shfl_up(w, d, 16);
      if (tid >= d) w += t;
    }
    wsum[tid] = w;
  }
  __syncthreads();
  int incl = sv + (wid ? wsum[wid - 1] : 0);
  int excl = incl - c;
  if (g < N) {
    rowptr2[g] = make_int2(lo + excl, lo + excl + c);
    dinv[g] = rsqrtf((float)(c + 1));
  }
  cur[tid] = lo + excl;
  __syncthreads();
  for (int k = tid; k < szD; k += 1024) {
    int p = pb[k];
    int pos = atomicAdd(&cur[p & 1023], 1);
    colarr[pos] = ((unsigned)p) >> 10;
  }
}

// node features prescaled by own dinv (inline global bmax reduction over NB2<=128)
__global__ void k_node(const float* __restrict__ coords, const int* __restrict__ degsrc,
                       const float* __restrict__ dinv, const int* __restrict__ bmax, int NB2,
                       int N, float4* __restrict__ x0s) {
  __shared__ int sm[128];
  int tid = threadIdx.x;
  if (tid < 128) sm[tid] = (tid < NB2) ? bmax[tid] : 0;
  __syncthreads();
  if (tid < 64) { sm[tid] = max(sm[tid], sm[tid + 64]); }
  __syncthreads();
  if (tid < 32) { sm[tid] = max(sm[tid], sm[tid + 32]); }
  __syncthreads();
  if (tid < 16) { sm[tid] = max(sm[tid], sm[tid + 16]); }
  __syncthreads();
  if (tid < 8) { sm[tid] = max(sm[tid], sm[tid + 8]); }
  __syncthreads();
  if (tid < 4) { sm[tid] = max(sm[tid], sm[tid + 4]); }
  __syncthreads();
  if (tid < 2) { sm[tid] = max(sm[tid], sm[tid + 2]); }
  __syncthreads();
  if (tid == 0) sm[0] = max(sm[0], sm[1]);
  __syncthreads();
  float inv = 1.0f / (float)max(sm[0], 1);
  int n = blockIdx.x * 256 + tid;
  if (n >= N) return;
  float di = dinv[n];
  float4 v;
  v.x = coords[n * 2 + 0] * di;
  v.y = coords[n * 2 + 1] * di;
  v.z = (float)degsrc[n] * inv * di;
  v.w = 0.f;
  x0s[n] = v;
}

// ---------------- fused layer-1: aggregate 3 feats + linear + relu + prescale -> fp8 ----
__global__ void k_agg3lin(const float4* __restrict__ x0s, const float* __restrict__ dinv,
                          const int2* __restrict__ rowptr2, const int* __restrict__ col,
                          const float* __restrict__ W1, const float* __restrict__ b1, int N,
                          unsigned int* __restrict__ x1f8) {
  __shared__ float w0s[128], w1s[128], w2s[128], bsm[128];
  for (int t = threadIdx.x; t < 128; t += 256) {
    w0s[t] = W1[t];
    w1s[t] = W1[128 + t];
    w2s[t] = W1[256 + t];
    bsm[t] = b1[t];
  }
  __syncthreads();
  int n = blockIdx.x * 256 + threadIdx.x;
  if (n >= N) return;
  float4 a = x0s[n];
  int2 rp = rowptr2[n];
  int k = rp.x, en = rp.y;
  for (; k + 3 < en; k += 4) {
    int s0 = col[k], s1 = col[k + 1], s2 = col[k + 2], s3 = col[k + 3];
    float4 w0 = x0s[s0];
    float4 w1 = x0s[s1];
    float4 w2 = x0s[s2];
    float4 w3 = x0s[s3];
    a.x += (w0.x + w1.x) + (w2.x + w3.x);
    a.y += (w0.y + w1.y) + (w2.y + w3.y);
    a.z += (w0.z + w1.z) + (w2.z + w3.z);
  }
  for (; k < en; k++) {
    float4 w = x0s[col[k]];
    a.x += w.x; a.y += w.y; a.z += w.z;
  }
  float di = dinv[n];
  float ax = a.x * di, ay = a.y * di, az = a.z * di;
  unsigned int* orow = x1f8 + (size_t)n * 32;
#pragma unroll 8
  for (int f0 = 0; f0 < 128; f0 += 4) {
    float v0 = fmaxf(bsm[f0] + ax * w0s[f0] + ay * w1s[f0] + az * w2s[f0], 0.f) * di;
    float v1 = fmaxf(bsm[f0 + 1] + ax * w0s[f0 + 1] + ay * w1s[f0 + 1] + az * w2s[f0 + 1], 0.f) * di;
    float v2 = fmaxf(bsm[f0 + 2] + ax * w0s[f0 + 2] + ay * w1s[f0 + 2] + az * w2s[f0 + 2], 0.f) * di;
    float v3 = fmaxf(bsm[f0 + 3] + ax * w0s[f0 + 3] + ay * w1s[f0 + 3] + az * w2s[f0 + 3], 0.f) * di;
    orow[f0 >> 2] = pk4_fp8(v0, v1, v2, v3);
  }
}

// ---------------- GCN layer 2 aggregation: fp8 gather, 8 lanes/node x uint4, 4-deep ----
__global__ void k_agg128(const unsigned int* __restrict__ x1f8, const float* __restrict__ dinv,
                         const int2* __restrict__ rowptr2, const int* __restrict__ col,
                         int N, unsigned short* __restrict__ xa) {
  int g = (int)((blockIdx.x * 256 + threadIdx.x) >> 3);
  int lane = threadIdx.x & 7;
  if (g >= N) return;
  const uint4* base = (const uint4*)x1f8 + lane;  // row stride = 8 uint4 (128 B)
  float acc[16];
#pragma unroll
  for (int i = 0; i < 16; i++) acc[i] = 0.f;
  uint4 self = base[(size_t)g * 8];
  acc4_fp8(self.x, acc); acc4_fp8(self.y, acc + 4);
  acc4_fp8(self.z, acc + 8); acc4_fp8(self.w, acc + 12);
  int2 rp = rowptr2[g];
  int k = rp.x, en = rp.y;
  for (; k + 3 < en; k += 4) {
    int s0 = col[k], s1 = col[k + 1], s2 = col[k + 2], s3 = col[k + 3];
    uint4 w0 = base[(size_t)s0 * 8];
    uint4 w1 = base[(size_t)s1 * 8];
    uint4 w2 = base[(size_t)s2 * 8];
    uint4 w3 = base[(size_t)s3 * 8];
    acc4_fp8(w0.x, acc); acc4_fp8(w0.y, acc + 4); acc4_fp8(w0.z, acc + 8); acc4_fp8(w0.w, acc + 12);
    acc4_fp8(w1.x, acc); acc4_fp8(w1.y, acc + 4); acc4_fp8(w1.z, acc + 8); acc4_fp8(w1.w, acc + 12);
    acc4_fp8(w2.x, acc); acc4_fp8(w2.y, acc + 4); acc4_fp8(w2.z, acc + 8); acc4_fp8(w2.w, acc + 12);
    acc4_fp8(w3.x, acc); acc4_fp8(w3.y, acc + 4); acc4_fp8(w3.z, acc + 8); acc4_fp8(w3.w, acc + 12);
  }
  for (; k < en; k++) {
    uint4 w = base[(size_t)col[k] * 8];
    acc4_fp8(w.x, acc); acc4_fp8(w.y, acc + 4); acc4_fp8(w.z, acc + 8); acc4_fp8(w.w, acc + 12);
  }
  float di = dinv[g];
  uint4 o1, o2;
  o1.x = pack2(acc[0] * di, acc[1] * di);
  o1.y = pack2(acc[2] * di, acc[3] * di);
  o1.z = pack2(acc[4] * di, acc[5] * di);
  o1.w = pack2(acc[6] * di, acc[7] * di);
  o2.x = pack2(acc[8] * di, acc[9] * di);
  o2.y = pack2(acc[10] * di, acc[11] * di);
  o2.z = pack2(acc[12] * di, acc[13] * di);
  o2.w = pack2(acc[14] * di, acc[15] * di);
  uint4* op = (uint4*)xa + (size_t)g * 16 + lane * 2;
  op[0] = o1;
  op[1] = o2;
}

// ---------------- layer 2 GEMM via MFMA, fused heads + colsum (x2 never stored) ----------
__global__ __launch_bounds__(256) void k_gemm2(const unsigned short* __restrict__ xab,
                                               const unsigned short* __restrict__ W2T,
                                               const float* __restrict__ b2,
                                               const float* __restrict__ Ws,
                                               const float* __restrict__ bs,
                                               const float* __restrict__ Wmu,
                                               const float* __restrict__ bmu,
                                               const float* __restrict__ Wls,
                                               const float* __restrict__ bls,
                                               int N, float* __restrict__ s_arr,
                                               float* __restrict__ out,
                                               float* __restrict__ partials) {
  __shared__ float w[640];
  __shared__ float cs[4][128];
  for (int t = threadIdx.x; t < 128; t += 256) {
    w[t] = Ws[t];
    w[128 + t] = Wmu[t * 2 + 0];
    w[256 + t] = Wmu[t * 2 + 1];
    w[384 + t] = Wls[t * 2 + 0];
    w[512 + t] = Wls[t * 2 + 1];
  }
  __syncthreads();
  int wv = threadIdx.x >> 6;
  int lane = threadIdx.x & 63;
  int l15 = lane & 15, lhi = lane >> 4;
  int rowbase = blockIdx.x * 64 + wv * 16;
  int arow = rowbase + l15;
  int arowc = min(arow, N - 1);
  const unsigned short* ap = xab + (size_t)arowc * HID + lhi * 8;
  bf16x8 a[4];
#pragma unroll
  for (int kk = 0; kk < 4; kk++) a[kk] = *(const bf16x8*)(ap + kk * 32);
  float cpart[8];
  float p0[4] = {0, 0, 0, 0}, p1[4] = {0, 0, 0, 0}, p2[4] = {0, 0, 0, 0};
  float p3[4] = {0, 0, 0, 0}, p4[4] = {0, 0, 0, 0};
#pragma unroll
  for (int ct = 0; ct < 8; ct++) {
    f32x4 acc = {0.f, 0.f, 0.f, 0.f};
    const unsigned short* bp = W2T + (size_t)(ct * 16 + l15) * HID + lhi * 8;
#pragma unroll
    for (int kk = 0; kk < 4; kk++) {
      bf16x8 bfr = *(const bf16x8*)(bp + kk * 32);
      acc = __builtin_amdgcn_mfma_f32_16x16x32_bf16(a[kk], bfr, acc, 0, 0, 0);
    }
    int cidx = ct * 16 + l15;
    float bias = b2[cidx];
    float ws_ = w[cidx];
    float wm0 = w[128 + cidx], wm1 = w[256 + cidx];
    float wl0 = w[384 + cidx], wl1 = w[512 + cidx];
    float cl = 0.f;
#pragma unroll
    for (int r = 0; r < 4; r++) {
      int node = rowbase + lhi * 4 + r;
      float o = fmaxf(acc[r] + bias, 0.f);
      if (node < N) cl += o;
      p0[r] += o * ws_;
      p1[r] += o * wm0;
      p2[r] += o * wm1;
      p3[r] += o * wl0;
      p4[r] += o * wl1;
    }
    cl += __shfl_xor(cl, 16);
    cl += __shfl_xor(cl, 32);
    cpart[ct] = cl;
  }
#pragma unroll
  for (int r = 0; r < 4; r++) {
#pragma unroll
    for (int m = 1; m < 16; m <<= 1) {
      p0[r] += __shfl_xor(p0[r], m);
      p1[r] += __shfl_xor(p1[r], m);
      p2[r] += __shfl_xor(p2[r], m);
      p3[r] += __shfl_xor(p3[r], m);
      p4[r] += __shfl_xor(p4[r], m);
    }
  }
  if (l15 == 0) {
#pragma unroll
    for (int r = 0; r < 4; r++) {
      int node = rowbase + lhi * 4 + r;
      if (node < N) {
        s_arr[node] = p0[r] + bs[0];
        out[(size_t)N + node * 2 + 0] = p1[r] + bmu[0];
        out[(size_t)N + node * 2 + 1] = p2[r] + bmu[1];
        out[(size_t)3 * N + node * 2 + 0] = fminf(fmaxf(p3[r] + bls[0], -4.f), 2.f);
        out[(size_t)3 * N + node * 2 + 1] = fminf(fmaxf(p4[r] + bls[1], -4.f), 2.f);
      }
    }
  }
  if (lane < 16) {
#pragma unroll
    for (int ct = 0; ct < 8; ct++) cs[wv][ct * 16 + lane] = cpart[ct];
  }
  __syncthreads();
  if (threadIdx.x < 128) {
    int f = threadIdx.x;
    partials[(size_t)blockIdx.x * 128 + f] = cs[0][f] + cs[1][f] + cs[2][f] + cs[3][f];
  }
}

// ---------------- merged: online-LSE partials (blocks 0..255) + colsum reduce (256..319) ----
__global__ void k_lse_colsum(const float* __restrict__ s, int N, float* __restrict__ pm,
                             float* __restrict__ pt, const float* __restrict__ partials,
                             int nblkG, float* __restrict__ colsum) {
  if (blockIdx.x >= 256) {
    int bb = blockIdx.x - 256;
    int f = threadIdx.x;
    if (f < 128) {
      float t = 0.f;
      for (int b = bb; b < nblkG; b += 64) t += partials[(size_t)b * 128 + f];
      atomicAdd(&colsum[f], t);
    }
    return;
  }
  __shared__ float smM[256], smT[256];
  float m = -1e30f, t = 0.f;
  for (int i = blockIdx.x * 256 + threadIdx.x; i < N; i += 256 * 256) {
    float v = s[i];
    if (v > m) { t = t * __expf(m - v) + 1.f; m = v; }
    else t += __expf(v - m);
  }
  smM[threadIdx.x] = m; smT[threadIdx.x] = t; __syncthreads();
  for (int st = 128; st > 0; st >>= 1) {
    if (threadIdx.x < st) {
      float m2 = smM[threadIdx.x + st], t2 = smT[threadIdx.x + st];
      float m1 = smM[threadIdx.x], t1 = smT[threadIdx.x];
      float M = fmaxf(m1, m2);
      smM[threadIdx.x] = M;
      smT[threadIdx.x] = t1 * __expf(m1 - M) + t2 * __expf(m2 - M);
    }
    __syncthreads();
  }
  if (threadIdx.x == 0) { pm[blockIdx.x] = smM[0]; pt[blockIdx.x] = smT[0]; }
}

// ---------------- merged: logits (inline LSE finish) + value head (last block) ----------
__global__ void k_logits_value(const float* __restrict__ sarr, const float* __restrict__ pm,
                               const float* __restrict__ pt, int N, float* __restrict__ out,
                               const float* __restrict__ colsum, const float* __restrict__ Wv1,
                               const float* __restrict__ bv1, const float* __restrict__ Wv2,
                               const float* __restrict__ bv2, int nblkN) {
  if ((int)blockIdx.x == nblkN) {
    __shared__ float hid[64];
    float invN = 1.0f / (float)N;
    int j = threadIdx.x;
    if (j < 64) {
      float a = bv1[j];
      for (int f = 0; f < 128; f++) a += (colsum[f] * invN) * Wv1[f * 64 + j];
      hid[j] = fmaxf(a, 0.f) * Wv2[j];
    }
    __syncthreads();
    if (threadIdx.x == 0) {
      float v = bv2[0];
      for (int jj = 0; jj < 64; jj++) v += hid[jj];
      out[(size_t)5 * N] = v;
    }
    return;
  }
  __shared__ float smM[256], smT[256];
  smM[threadIdx.x] = pm[threadIdx.x];
  smT[threadIdx.x] = pt[threadIdx.x];
  __syncthreads();
  for (int st = 128; st > 0; st >>= 1) {
    if (threadIdx.x < st) {
      float m2 = smM[threadIdx.x + st], t2 = smT[threadIdx.x + st];
      float m1 = smM[threadIdx.x], t1 = smT[threadIdx.x];
      float M = fmaxf(m1, m2);
      smM[threadIdx.x] = M;
      smT[threadIdx.x] = t1 * __expf(m1 - M) + t2 * __expf(m2 - M);
    }
    __syncthreads();
  }
  float lse = smM[0] + logf(smT[0]);
  int n = blockIdx.x * 256 + threadIdx.x;
  if (n < N) out[n] = sarr[n] - lse;
}

extern "C" void kernel_launch(void* const* d_in, const int* in_sizes, int n_in,
                              void* d_out, int out_size, void* d_ws, size_t ws_size,
                              hipStream_t stream) {
  const float* coords = (const float*)d_in[0];
  const int* ei = (const int*)d_in[1];
  const float* W1 = (const float*)d_in[2];
  const float* b1 = (const float*)d_in[3];
  const float* W2 = (const float*)d_in[4];
  const float* b2 = (const float*)d_in[5];
  const float* Wsw = (const float*)d_in[6];
  const float* bsw = (const float*)d_in[7];
  const float* Wmu = (const float*)d_in[8];
  const float* bmu = (const float*)d_in[9];
  const float* Wls = (const float*)d_in[10];
  const float* bls = (const float*)d_in[11];
  const float* Wv1 = (const float*)d_in[12];
  const float* bv1 = (const float*)d_in[13];
  const float* Wv2 = (const float*)d_in[14];
  const float* bv2 = (const float*)d_in[15];
  int N = in_sizes[0] / 2;
  int E = in_sizes[1] / 2;
  const int* src = ei;
  const int* dst = ei + E;
  float* outf = (float*)d_out;
  int NB2 = (N + 1023) >> 10;
  int CAP = ((E / NB2) * 5 / 4 + 1024 + 255) & ~255;
  int nblkG = (N + 63) / 64;
  int nblkN = (N + 255) / 256;

  char* base = (char*)d_ws;
  size_t off = 0;
  auto alloc = [&](size_t bytes) -> void* {
    void* r = base + off;
    off += (bytes + 255) & ~(size_t)255;
    return r;
  };
  size_t zero_start = off;
  int* curd = (int*)alloc((size_t)NB2 * 4);
  int* curs = (int*)alloc((size_t)NB2 * 4);
  float* colsum = (float*)alloc(128 * 4);
  size_t zero_bytes = off - zero_start;
  int* bmax = (int*)alloc((size_t)NB2 * 4);
  int2* rowptr2 = (int2*)alloc((size_t)N * 8);
  int* pairsp = (int*)alloc((size_t)NB2 * CAP * 4);
  unsigned short* srcb = (unsigned short*)alloc((size_t)NB2 * CAP * 2);
  int* colarr = (int*)alloc((size_t)NB2 * CAP * 4);
  int* degsrc = (int*)alloc((size_t)N * 4);
  float* dinv = (float*)alloc((size_t)N * 4);
  float4* x0s = (float4*)alloc((size_t)N * 16);
  float* sarr = (float*)alloc((size_t)N * 4);
  float* pm = (float*)alloc(256 * 4);
  float* pt = (float*)alloc(256 * 4);
  unsigned short* W2T = (unsigned short*)alloc(128 * 128 * 2);
  float* partials = (float*)alloc((size_t)nblkG * 128 * 4);
  unsigned int* x1f8 = (unsigned int*)alloc((size_t)N * 128);      // fp8 e4m3, N x 128
  unsigned short* xab = (unsigned short*)alloc((size_t)N * HID * 2);
  if (off > ws_size) return;

  hipMemsetAsync(base + zero_start, 0, zero_bytes, stream);
  k_scatter2<<<512, 256, 0, stream>>>(src, dst, E, NB2, CAP, curd, curs, pairsp, srcb);
  k_degcsr<<<2 * NB2 + 16, 1024, 0, stream>>>(srcb, curs, pairsp, curd, NB2, CAP, N, degsrc,
                                              bmax, rowptr2, dinv, colarr, W2, W2T);
  k_node<<<nblkN, 256, 0, stream>>>(coords, degsrc, dinv, bmax, NB2, N, x0s);
  k_agg3lin<<<nblkN, 256, 0, stream>>>(x0s, dinv, rowptr2, colarr, W1, b1, N, x1f8);
  k_agg128<<<(N * 8 + 255) / 256, 256, 0, stream>>>(x1f8, dinv, rowptr2, colarr, N, xab);
  k_gemm2<<<nblkG, 256, 0, stream>>>(xab, W2T, b2, Wsw, bsw, Wmu, bmu, Wls, bls, N, sarr, outf,
                                     partials);
  k_lse_colsum<<<320, 256, 0, stream>>>(sarr, N, pm, pt, partials, nblkG, colsum);
  k_logits_value<<<nblkN + 1, 256, 0, stream>>>(sarr, pm, pt, N, outf, colsum, Wv1, bv1, Wv2,
                                                bv2, nblkN);
}